// Round 7
// baseline (167.830 us; speedup 1.0000x reference)
//
#include <hip/hip_runtime.h>

#define OUT_DIM 300

typedef _Float16 half2_t __attribute__((ext_vector_type(2)));
typedef _Float16 half4_t __attribute__((ext_vector_type(4)));

// ---------------------------------------------------------------------------
// Fused setup: blocks [0, scat_blocks) do row_ptr boundary-scatter; the rest
// repack fp32 weights -> f16, 8 slices, stride-128 rows (one cache line each).
// Slice s covers cols [38s, 38s+38) (s=7: 34 cols). uint-chunk k of row r:
// wf[(s*in_dim + r)*128 + (k-19s)*4] = half2(w[r][2k], w[r][2k+1]).
__global__ __launch_bounds__(256) void setup8_kernel(
    const int* __restrict__ rows, int* __restrict__ row_ptr,
    const float* __restrict__ w, unsigned char* __restrict__ wf,
    int nnz, int batch, int in_dim, int scat_blocks)
{
    if ((int)blockIdx.x < scat_blocks) {
        int i = blockIdx.x * 256 + threadIdx.x;
        if (i >= nnz) return;
        int r = rows[i];
        int prev = (i == 0) ? -1 : rows[i - 1];
        for (int q = prev + 1; q <= r; ++q) row_ptr[q] = i;
        if (i == nnz - 1)
            for (int q = r + 1; q <= batch; ++q) row_ptr[q] = nnz;
        return;
    }
    const int UPR = OUT_DIM / 2;          // 150 uint-chunks per weight row
    int j = ((int)blockIdx.x - scat_blocks) * 256 + threadIdx.x;
    if (j >= in_dim * UPR) return;
    int r = j / UPR;
    int k = j - r * UPR;                  // 0..149, cols 2k,2k+1
    int s = k / 19;                       // 0..7
    int kc = k - s * 19;
    float2 f = *(const float2*)(w + (size_t)r * OUT_DIM + 2 * k);
    half2_t h;
    h.x = (_Float16)f.x;
    h.y = (_Float16)f.y;
    *(half2_t*)(wf + ((size_t)s * in_dim + r) * 128 + kc * 4) = h;
}

// ---------------------------------------------------------------------------
// 8-slice SpMM: block b = (rowgroup b>>3: 4 rows, one per wave; slice b&7).
// Round-robin block->XCD => XCD x touches only slice x: 3.84 MB, L2-resident.
// Wave: grp = lane/19 (0..2 real, 3 = prefetch of next round's grp-0 line),
// ch = lane-19*grp owns uint chunk (2 cols) -> float2 register accumulator.
__global__ __launch_bounds__(256) void spmm8(
    const int* __restrict__ row_ptr,
    const int* __restrict__ cols,
    const float* __restrict__ vals,
    const unsigned char* __restrict__ wf,
    const float* __restrict__ bias,
    float* __restrict__ out,
    int batch, int in_dim)
{
    __shared__ uint2 sh[4][76];

    const int slice = blockIdx.x & 7;
    const int wave  = threadIdx.x >> 6;
    const int lane  = threadIdx.x & 63;
    const int row   = (blockIdx.x >> 3) * 4 + wave;
    if (row >= batch) return;

    const int grp = lane / 19;            // 0..3
    const int ch  = lane - grp * 19;      // 0..18 (grp3: 0..6)
    const int choff = ch * 4;

    const unsigned char* wslice = wf + (size_t)slice * in_dim * 128;
    uint2* shw = sh[wave];                // wave-private: no __syncthreads

    const int lo = row_ptr[row];
    const int hi = row_ptr[row + 1];

    float2 acc = make_float2(0.f, 0.f);

    for (int base = lo; base < hi; base += 64) {
        const int rem = hi - base;
        const int cnt = rem < 64 ? rem : 64;

        uint2 ov = make_uint2(0u, 0u);
        if (lane < cnt) {
            ov.x = (unsigned)cols[base + lane] << 7;     // byte offset, stride 128
            ov.y = __float_as_uint(vals[base + lane]);
        }
        shw[lane] = ov;
        if (lane < 12) shw[64 + lane] = make_uint2(0u, 0u);  // pad slots 64..75

        const int rr  = (cnt + 2) / 3;        // rounds of 3 nnz, <= 22
        const int rrp = (rr + 7) & ~7;        // <= 24 -> max slot 3*23+3 = 72
        for (int r0 = 0; r0 < rrp; r0 += 8) {
#pragma unroll
            for (int u = 0; u < 8; ++u) {
                uint2 q = shw[3 * (r0 + u) + grp];       // broadcast per group
                float v = __uint_as_float(q.y);
                half2_t wv = *(const half2_t*)(wslice + q.x + choff);
                acc.x += v * (float)wv.x;                // v_fma_mix_f32
                acc.y += v * (float)wv.y;
            }
        }
        // Zero-padded slots: v=0, off=0 -> contributes 0 via hot line 0.
        // grp3 lanes read next round's grp0 line (prefetch); never stored.
    }

    // Fold the 3 real groups: lane i (<19) += lanes i+19, i+38.
    float ax = acc.x + __shfl_down(acc.x, 19) + __shfl_down(acc.x, 38);
    float ay = acc.y + __shfl_down(acc.y, 19) + __shfl_down(acc.y, 38);

    const int nch = (slice == 7) ? 17 : 19;
    if (lane < nch) {
        const int col = slice * 38 + 2 * lane;           // even -> 8B aligned
        const float2 b = *(const float2*)(bias + col);
        float2 rv;
        rv.x = fmaxf(ax + b.x, 0.f);
        rv.y = fmaxf(ay + b.y, 0.f);
        *(float2*)(out + (size_t)row * OUT_DIM + col) = rv;
    }
}

// ---------------------------------------------------------------------------
// Fallback tier: R6 4-slice layout (needs only ~19.2 MB ws).
__global__ __launch_bounds__(256) void repack_f16_sliced(
    const float* __restrict__ w, unsigned char* __restrict__ wf, int in_dim)
{
    const int PPR = OUT_DIM / 2;
    int i = blockIdx.x * 256 + threadIdx.x;
    if (i >= in_dim * PPR) return;
    int row = i / PPR;
    int p   = i - row * PPR;
    int s   = p / 38;
    int pc  = p - s * 38;
    size_t dst = (size_t)s * in_dim * 160 + (size_t)row * 160 + (size_t)pc * 4;
    float2 f = *(const float2*)(w + (size_t)row * OUT_DIM + 2 * p);
    half2_t h;
    h.x = (_Float16)f.x;
    h.y = (_Float16)f.y;
    *(half2_t*)(wf + dst) = h;
}

__global__ __launch_bounds__(256) void row_ptr_scatter(
    const int* __restrict__ rows, int* __restrict__ row_ptr, int nnz, int batch)
{
    int i = blockIdx.x * 256 + threadIdx.x;
    if (i >= nnz) return;
    int r = rows[i];
    int prev = (i == 0) ? -1 : rows[i - 1];
    for (int q = prev + 1; q <= r; ++q) row_ptr[q] = i;
    if (i == nnz - 1)
        for (int q = r + 1; q <= batch; ++q) row_ptr[q] = nnz;
}

__global__ __launch_bounds__(256) void spmm_sliced3(
    const int* __restrict__ row_ptr,
    const int* __restrict__ cols,
    const float* __restrict__ vals,
    const unsigned char* __restrict__ wf,
    const float* __restrict__ bias,
    float* __restrict__ out,
    int batch, int in_dim)
{
    __shared__ uint2 sh[4][76];

    const int slice = blockIdx.x & 3;
    const int wave  = threadIdx.x >> 6;
    const int lane  = threadIdx.x & 63;
    const int row   = (blockIdx.x >> 2) * 4 + wave;
    if (row >= batch) return;

    const int nch = (slice == 3) ? 18 : 19;
    const unsigned char* wslice = wf + (size_t)slice * in_dim * 160;

    int grp = lane / nch;
    int ch  = lane - grp * nch;
    const int choff = ch * 8;
    uint2* shw = sh[wave];

    const int lo = row_ptr[row];
    const int hi = row_ptr[row + 1];
    float4 acc = make_float4(0.f, 0.f, 0.f, 0.f);

    for (int base = lo; base < hi; base += 64) {
        const int rem = hi - base;
        const int cnt = rem < 64 ? rem : 64;
        uint2 ov = make_uint2(0u, 0u);
        if (lane < cnt) {
            ov.x = (unsigned)(cols[base + lane] * 160);
            ov.y = __float_as_uint(vals[base + lane]);
        }
        shw[lane] = ov;
        if (lane < 12) shw[64 + lane] = make_uint2(0u, 0u);

        const int rr  = (cnt + 2) / 3;
        const int rrp = (rr + 3) & ~3;
        for (int r0 = 0; r0 < rrp; r0 += 4) {
#pragma unroll
            for (int u = 0; u < 4; ++u) {
                uint2 q = shw[3 * (r0 + u) + grp];
                float v = __uint_as_float(q.y);
                half4_t wv = *(const half4_t*)(wslice + q.x + choff);
                acc.x += v * (float)wv.x;
                acc.y += v * (float)wv.y;
                acc.z += v * (float)wv.z;
                acc.w += v * (float)wv.w;
            }
        }
    }

    float ax = acc.x + __shfl_down(acc.x, nch) + __shfl_down(acc.x, 2 * nch);
    float ay = acc.y + __shfl_down(acc.y, nch) + __shfl_down(acc.y, 2 * nch);
    float az = acc.z + __shfl_down(acc.z, nch) + __shfl_down(acc.z, 2 * nch);
    float aw = acc.w + __shfl_down(acc.w, nch) + __shfl_down(acc.w, 2 * nch);

    if (lane < nch) {
        const int colb = 76 * slice + 4 * lane;
        const float4 b = *(const float4*)(bias + colb);
        float4 rv;
        rv.x = fmaxf(ax + b.x, 0.f);
        rv.y = fmaxf(ay + b.y, 0.f);
        rv.z = fmaxf(az + b.z, 0.f);
        rv.w = fmaxf(aw + b.w, 0.f);
        *(float4*)(out + (size_t)row * OUT_DIM + colb) = rv;
    }
}

// ---------------------------------------------------------------------------
// Last-resort fp32 path.
__global__ __launch_bounds__(256) void spmm_wave_f32_kernel(
    const int* __restrict__ row_ptr,
    const int* __restrict__ cols,
    const float* __restrict__ vals,
    const float* __restrict__ weights,
    const float* __restrict__ bias,
    float* __restrict__ out,
    int batch)
{
    const int wave = threadIdx.x >> 6;
    const int lane = threadIdx.x & 63;
    const int row  = blockIdx.x * 4 + wave;
    if (row >= batch) return;

    const int lo = row_ptr[row];
    const int hi = row_ptr[row + 1];
    float4 acc0 = make_float4(0.f, 0.f, 0.f, 0.f);
    float4 acc1 = make_float4(0.f, 0.f, 0.f, 0.f);
    const bool tail = (lane < 75 - 64);

    for (int base = lo; base < hi; base += 64) {
        const int rem = hi - base;
        const int cnt = rem < 64 ? rem : 64;
        int   c = 0;
        float v = 0.0f;
        if (lane < cnt) { c = cols[base + lane]; v = vals[base + lane]; }
        const int rounds = (cnt + 7) & ~7;
        for (int k = 0; k < rounds; k += 8) {
#pragma unroll
            for (int u = 0; u < 8; ++u) {
                const int   cc = __shfl(c, k + u);
                const float vv = __shfl(v, k + u);
                const float4* wrow = (const float4*)(weights + (size_t)cc * OUT_DIM);
                float4 w0 = wrow[lane];
                acc0.x += vv * w0.x; acc0.y += vv * w0.y;
                acc0.z += vv * w0.z; acc0.w += vv * w0.w;
                if (tail) {
                    float4 w1 = wrow[64 + lane];
                    acc1.x += vv * w1.x; acc1.y += vv * w1.y;
                    acc1.z += vv * w1.z; acc1.w += vv * w1.w;
                }
            }
        }
    }

    const float4* b4 = (const float4*)bias;
    float4* orow = (float4*)(out + (size_t)row * OUT_DIM);
    float4 b0 = b4[lane];
    float4 r0;
    r0.x = fmaxf(acc0.x + b0.x, 0.f);
    r0.y = fmaxf(acc0.y + b0.y, 0.f);
    r0.z = fmaxf(acc0.z + b0.z, 0.f);
    r0.w = fmaxf(acc0.w + b0.w, 0.f);
    orow[lane] = r0;
    if (tail) {
        float4 b1 = b4[64 + lane];
        float4 r1;
        r1.x = fmaxf(acc1.x + b1.x, 0.f);
        r1.y = fmaxf(acc1.y + b1.y, 0.f);
        r1.z = fmaxf(acc1.z + b1.z, 0.f);
        r1.w = fmaxf(acc1.w + b1.w, 0.f);
        orow[64 + lane] = r1;
    }
}

// ---------------------------------------------------------------------------
extern "C" void kernel_launch(void* const* d_in, const int* in_sizes, int n_in,
                              void* d_out, int out_size, void* d_ws, size_t ws_size,
                              hipStream_t stream) {
    const int*   sp_rows = (const int*)d_in[0];
    const int*   sp_cols = (const int*)d_in[1];
    const float* sp_vals = (const float*)d_in[2];
    const float* weights = (const float*)d_in[3];
    const float* bias    = (const float*)d_in[4];
    float* out = (float*)d_out;

    const int nnz    = in_sizes[0];
    const int w_elts = in_sizes[3];
    const int in_dim = w_elts / OUT_DIM;           // 30000
    const int batch  = out_size / OUT_DIM;         // 16384

    size_t rp_bytes = (size_t)(batch + 1) * sizeof(int);
    size_t wf_off   = (rp_bytes + 255) & ~(size_t)255;
    size_t need8    = wf_off + (size_t)in_dim * 8 * 128 + 256;  // 30.7 MB
    size_t need4    = wf_off + (size_t)in_dim * 4 * 160 + 256;  // 19.2 MB

    int* row_ptr = (int*)d_ws;
    const int rowgroups = (batch + 3) / 4;

    if (ws_size >= need8) {
        unsigned char* wf = (unsigned char*)d_ws + wf_off;
        const int scat_blocks = (nnz + 255) / 256;
        const int rep_blocks  = (in_dim * (OUT_DIM / 2) + 255) / 256;
        setup8_kernel<<<scat_blocks + rep_blocks, 256, 0, stream>>>(
            sp_rows, row_ptr, weights, wf, nnz, batch, in_dim, scat_blocks);
        spmm8<<<rowgroups * 8, 256, 0, stream>>>(
            row_ptr, sp_cols, sp_vals, wf, bias, out, batch, in_dim);
    } else if (ws_size >= need4) {
        unsigned char* wf = (unsigned char*)d_ws + wf_off;
        row_ptr_scatter<<<(nnz + 255) / 256, 256, 0, stream>>>(
            sp_rows, row_ptr, nnz, batch);
        const int pairs = in_dim * (OUT_DIM / 2);
        repack_f16_sliced<<<(pairs + 255) / 256, 256, 0, stream>>>(
            weights, wf, in_dim);
        spmm_sliced3<<<rowgroups * 4, 256, 0, stream>>>(
            row_ptr, sp_cols, sp_vals, wf, bias, out, batch, in_dim);
    } else {
        row_ptr_scatter<<<(nnz + 255) / 256, 256, 0, stream>>>(
            sp_rows, row_ptr, nnz, batch);
        spmm_wave_f32_kernel<<<(batch + 3) / 4, 256, 0, stream>>>(
            row_ptr, sp_cols, sp_vals, weights, bias, out, batch);
    }
}

// Round 8
// 159.292 us; speedup vs baseline: 1.0536x; 1.0536x over previous
//
#include <hip/hip_runtime.h>

#define OUT_DIM 300

typedef _Float16 half2_t __attribute__((ext_vector_type(2)));
typedef _Float16 half4_t __attribute__((ext_vector_type(4)));

// ---------------------------------------------------------------------------
// Fused setup: blocks [0, scat_blocks) scatter row_ptr; remainder repack fp32
// weights -> f16, 8 slices x stride-128 rows. Slice s covers cols
// [40s, 40s+40) (s=7: 20 cols). uint-chunk k (cols 2k,2k+1) of row r:
// wf[(s*in_dim + r)*128 + (k-20s)*4].  Payload 80 B inside ONE 128 B line.
__global__ __launch_bounds__(256) void setup8_kernel(
    const int* __restrict__ rows, int* __restrict__ row_ptr,
    const float* __restrict__ w, unsigned char* __restrict__ wf,
    int nnz, int batch, int in_dim, int scat_blocks)
{
    if ((int)blockIdx.x < scat_blocks) {
        int i = blockIdx.x * 256 + threadIdx.x;
        if (i >= nnz) return;
        int r = rows[i];
        int prev = (i == 0) ? -1 : rows[i - 1];
        for (int q = prev + 1; q <= r; ++q) row_ptr[q] = i;
        if (i == nnz - 1)
            for (int q = r + 1; q <= batch; ++q) row_ptr[q] = nnz;
        return;
    }
    const int UPR = OUT_DIM / 2;          // 150 uint-chunks per weight row
    int j = ((int)blockIdx.x - scat_blocks) * 256 + threadIdx.x;
    if (j >= in_dim * UPR) return;
    int r = j / UPR;
    int k = j - r * UPR;                  // 0..149 -> cols 2k, 2k+1
    int s = k / 20;                       // 0..7 (k=140..149 -> s=7)
    int kc = k - s * 20;                  // 0..19 (s=7: 0..9)
    float2 f = *(const float2*)(w + (size_t)r * OUT_DIM + 2 * k);
    half2_t h;
    h.x = (_Float16)f.x;
    h.y = (_Float16)f.y;
    *(half2_t*)(wf + ((size_t)s * in_dim + r) * 128 + kc * 4) = h;
}

// ---------------------------------------------------------------------------
// 8-slice wide-load SpMM. Block b: rowgroup b>>3 (4 rows, 1/wave), slice b&7.
// Round-robin block->XCD => XCD x touches only slice x: 3.84 MB, L2-resident,
// one 128 B line per (nnz, slice) access.
// Wave: 6 groups x 10 lanes (grp=lane/10, 0..5 real; lanes 60..63 grp=6
// duplicate next round's grp-0 line = free prefetch). Lane owns half4 chunk
// ch=lane-10*grp (4 cols) -> float4 register accumulator.
// Per round u: 1 ds_read_b64 + 1 global_load_dwordx2 + 4 v_fma_mix for 6 nnz.
__global__ __launch_bounds__(256) void spmm8w(
    const int* __restrict__ row_ptr,
    const int* __restrict__ cols,
    const float* __restrict__ vals,
    const unsigned char* __restrict__ wf,
    const float* __restrict__ bias,
    float* __restrict__ out,
    int batch, int in_dim)
{
    __shared__ uint2 sh[4][76];

    const int slice = blockIdx.x & 7;
    const int wave  = threadIdx.x >> 6;
    const int lane  = threadIdx.x & 63;
    const int row   = (blockIdx.x >> 3) * 4 + wave;
    if (row >= batch) return;

    const int grp = lane / 10;            // 0..6 (6 = prefetch lanes 60..63)
    const int ch  = lane - grp * 10;      // 0..9
    const int choff = ch * 8;

    const unsigned char* wslice = wf + (size_t)slice * in_dim * 128;
    uint2* shw = sh[wave];                // wave-private: no __syncthreads

    const int lo = row_ptr[row];
    const int hi = row_ptr[row + 1];

    float4 acc = make_float4(0.f, 0.f, 0.f, 0.f);

    for (int base = lo; base < hi; base += 64) {
        const int rem = hi - base;
        const int cnt = rem < 64 ? rem : 64;

        uint2 ov = make_uint2(0u, 0u);
        if (lane < cnt) {
            ov.x = (unsigned)cols[base + lane] << 7;   // byte offset (stride 128)
            ov.y = __float_as_uint(vals[base + lane]);
        }
        shw[lane] = ov;
        if (lane < 12) shw[64 + lane] = make_uint2(0u, 0u);  // pad slots 64..75

        const int rr  = (cnt + 5) / 6;        // rounds of 6 nnz, <= 11
        const int rrp = (rr + 3) & ~3;        // <= 12 -> max slot 6*11+6 = 72
        for (int r0 = 0; r0 < rrp; r0 += 4) {
#pragma unroll
            for (int u = 0; u < 4; ++u) {
                uint2 q = shw[6 * (r0 + u) + grp];     // broadcast per group
                float v = __uint_as_float(q.y);
                half4_t wv = *(const half4_t*)(wslice + q.x + choff);
                acc.x += v * (float)wv.x;              // v_fma_mix_f32
                acc.y += v * (float)wv.y;
                acc.z += v * (float)wv.z;
                acc.w += v * (float)wv.w;
            }
        }
        // Zero slots: v=0, off=0 -> +0 via hot line 0. grp6 = prefetch only.
    }

    // Fold groups 1..5 into group 0 (all shfls read pre-fold acc).
    float ax = acc.x + __shfl_down(acc.x, 10) + __shfl_down(acc.x, 20)
             + __shfl_down(acc.x, 30) + __shfl_down(acc.x, 40) + __shfl_down(acc.x, 50);
    float ay = acc.y + __shfl_down(acc.y, 10) + __shfl_down(acc.y, 20)
             + __shfl_down(acc.y, 30) + __shfl_down(acc.y, 40) + __shfl_down(acc.y, 50);
    float az = acc.z + __shfl_down(acc.z, 10) + __shfl_down(acc.z, 20)
             + __shfl_down(acc.z, 30) + __shfl_down(acc.z, 40) + __shfl_down(acc.z, 50);
    float aw = acc.w + __shfl_down(acc.w, 10) + __shfl_down(acc.w, 20)
             + __shfl_down(acc.w, 30) + __shfl_down(acc.w, 40) + __shfl_down(acc.w, 50);

    const int nch = (slice == 7) ? 5 : 10;           // half4 chunks stored
    if (lane < nch) {
        const int col = slice * 40 + 4 * lane;       // byte off 160s+16i: 16B-aligned
        const float4 b = *(const float4*)(bias + col);
        float4 rv;
        rv.x = fmaxf(ax + b.x, 0.f);
        rv.y = fmaxf(ay + b.y, 0.f);
        rv.z = fmaxf(az + b.z, 0.f);
        rv.w = fmaxf(aw + b.w, 0.f);
        *(float4*)(out + (size_t)row * OUT_DIM + col) = rv;
    }
}

// ---------------------------------------------------------------------------
// Fallback tier: R6 4-slice layout (~19.2 MB ws). Proven 45 us.
__global__ __launch_bounds__(256) void repack_f16_sliced(
    const float* __restrict__ w, unsigned char* __restrict__ wf, int in_dim)
{
    const int PPR = OUT_DIM / 2;
    int i = blockIdx.x * 256 + threadIdx.x;
    if (i >= in_dim * PPR) return;
    int row = i / PPR;
    int p   = i - row * PPR;
    int s   = p / 38;
    int pc  = p - s * 38;
    size_t dst = (size_t)s * in_dim * 160 + (size_t)row * 160 + (size_t)pc * 4;
    float2 f = *(const float2*)(w + (size_t)row * OUT_DIM + 2 * p);
    half2_t h;
    h.x = (_Float16)f.x;
    h.y = (_Float16)f.y;
    *(half2_t*)(wf + dst) = h;
}

__global__ __launch_bounds__(256) void row_ptr_scatter(
    const int* __restrict__ rows, int* __restrict__ row_ptr, int nnz, int batch)
{
    int i = blockIdx.x * 256 + threadIdx.x;
    if (i >= nnz) return;
    int r = rows[i];
    int prev = (i == 0) ? -1 : rows[i - 1];
    for (int q = prev + 1; q <= r; ++q) row_ptr[q] = i;
    if (i == nnz - 1)
        for (int q = r + 1; q <= batch; ++q) row_ptr[q] = nnz;
}

__global__ __launch_bounds__(256) void spmm_sliced3(
    const int* __restrict__ row_ptr,
    const int* __restrict__ cols,
    const float* __restrict__ vals,
    const unsigned char* __restrict__ wf,
    const float* __restrict__ bias,
    float* __restrict__ out,
    int batch, int in_dim)
{
    __shared__ uint2 sh[4][76];

    const int slice = blockIdx.x & 3;
    const int wave  = threadIdx.x >> 6;
    const int lane  = threadIdx.x & 63;
    const int row   = (blockIdx.x >> 2) * 4 + wave;
    if (row >= batch) return;

    const int nch = (slice == 3) ? 18 : 19;
    const unsigned char* wslice = wf + (size_t)slice * in_dim * 160;

    int grp = lane / nch;
    int ch  = lane - grp * nch;
    const int choff = ch * 8;
    uint2* shw = sh[wave];

    const int lo = row_ptr[row];
    const int hi = row_ptr[row + 1];
    float4 acc = make_float4(0.f, 0.f, 0.f, 0.f);

    for (int base = lo; base < hi; base += 64) {
        const int rem = hi - base;
        const int cnt = rem < 64 ? rem : 64;
        uint2 ov = make_uint2(0u, 0u);
        if (lane < cnt) {
            ov.x = (unsigned)(cols[base + lane] * 160);
            ov.y = __float_as_uint(vals[base + lane]);
        }
        shw[lane] = ov;
        if (lane < 12) shw[64 + lane] = make_uint2(0u, 0u);

        const int rr  = (cnt + 2) / 3;
        const int rrp = (rr + 3) & ~3;
        for (int r0 = 0; r0 < rrp; r0 += 4) {
#pragma unroll
            for (int u = 0; u < 4; ++u) {
                uint2 q = shw[3 * (r0 + u) + grp];
                float v = __uint_as_float(q.y);
                half4_t wv = *(const half4_t*)(wslice + q.x + choff);
                acc.x += v * (float)wv.x;
                acc.y += v * (float)wv.y;
                acc.z += v * (float)wv.z;
                acc.w += v * (float)wv.w;
            }
        }
    }

    float ax = acc.x + __shfl_down(acc.x, nch) + __shfl_down(acc.x, 2 * nch);
    float ay = acc.y + __shfl_down(acc.y, nch) + __shfl_down(acc.y, 2 * nch);
    float az = acc.z + __shfl_down(acc.z, nch) + __shfl_down(acc.z, 2 * nch);
    float aw = acc.w + __shfl_down(acc.w, nch) + __shfl_down(acc.w, 2 * nch);

    if (lane < nch) {
        const int colb = 76 * slice + 4 * lane;
        const float4 b = *(const float4*)(bias + colb);
        float4 rv;
        rv.x = fmaxf(ax + b.x, 0.f);
        rv.y = fmaxf(ay + b.y, 0.f);
        rv.z = fmaxf(az + b.z, 0.f);
        rv.w = fmaxf(aw + b.w, 0.f);
        *(float4*)(out + (size_t)row * OUT_DIM + colb) = rv;
    }
}

// ---------------------------------------------------------------------------
// Last-resort fp32 path.
__global__ __launch_bounds__(256) void spmm_wave_f32_kernel(
    const int* __restrict__ row_ptr,
    const int* __restrict__ cols,
    const float* __restrict__ vals,
    const float* __restrict__ weights,
    const float* __restrict__ bias,
    float* __restrict__ out,
    int batch)
{
    const int wave = threadIdx.x >> 6;
    const int lane = threadIdx.x & 63;
    const int row  = blockIdx.x * 4 + wave;
    if (row >= batch) return;

    const int lo = row_ptr[row];
    const int hi = row_ptr[row + 1];
    float4 acc0 = make_float4(0.f, 0.f, 0.f, 0.f);
    float4 acc1 = make_float4(0.f, 0.f, 0.f, 0.f);
    const bool tail = (lane < 75 - 64);

    for (int base = lo; base < hi; base += 64) {
        const int rem = hi - base;
        const int cnt = rem < 64 ? rem : 64;
        int   c = 0;
        float v = 0.0f;
        if (lane < cnt) { c = cols[base + lane]; v = vals[base + lane]; }
        const int rounds = (cnt + 7) & ~7;
        for (int k = 0; k < rounds; k += 8) {
#pragma unroll
            for (int u = 0; u < 8; ++u) {
                const int   cc = __shfl(c, k + u);
                const float vv = __shfl(v, k + u);
                const float4* wrow = (const float4*)(weights + (size_t)cc * OUT_DIM);
                float4 w0 = wrow[lane];
                acc0.x += vv * w0.x; acc0.y += vv * w0.y;
                acc0.z += vv * w0.z; acc0.w += vv * w0.w;
                if (tail) {
                    float4 w1 = wrow[64 + lane];
                    acc1.x += vv * w1.x; acc1.y += vv * w1.y;
                    acc1.z += vv * w1.z; acc1.w += vv * w1.w;
                }
            }
        }
    }

    const float4* b4 = (const float4*)bias;
    float4* orow = (float4*)(out + (size_t)row * OUT_DIM);
    float4 b0 = b4[lane];
    float4 r0;
    r0.x = fmaxf(acc0.x + b0.x, 0.f);
    r0.y = fmaxf(acc0.y + b0.y, 0.f);
    r0.z = fmaxf(acc0.z + b0.z, 0.f);
    r0.w = fmaxf(acc0.w + b0.w, 0.f);
    orow[lane] = r0;
    if (tail) {
        float4 b1 = b4[64 + lane];
        float4 r1;
        r1.x = fmaxf(acc1.x + b1.x, 0.f);
        r1.y = fmaxf(acc1.y + b1.y, 0.f);
        r1.z = fmaxf(acc1.z + b1.z, 0.f);
        r1.w = fmaxf(acc1.w + b1.w, 0.f);
        orow[64 + lane] = r1;
    }
}

// ---------------------------------------------------------------------------
extern "C" void kernel_launch(void* const* d_in, const int* in_sizes, int n_in,
                              void* d_out, int out_size, void* d_ws, size_t ws_size,
                              hipStream_t stream) {
    const int*   sp_rows = (const int*)d_in[0];
    const int*   sp_cols = (const int*)d_in[1];
    const float* sp_vals = (const float*)d_in[2];
    const float* weights = (const float*)d_in[3];
    const float* bias    = (const float*)d_in[4];
    float* out = (float*)d_out;

    const int nnz    = in_sizes[0];
    const int w_elts = in_sizes[3];
    const int in_dim = w_elts / OUT_DIM;           // 30000
    const int batch  = out_size / OUT_DIM;         // 16384

    size_t rp_bytes = (size_t)(batch + 1) * sizeof(int);
    size_t wf_off   = (rp_bytes + 255) & ~(size_t)255;
    size_t need8    = wf_off + (size_t)in_dim * 8 * 128 + 256;  // 30.7 MB
    size_t need4    = wf_off + (size_t)in_dim * 4 * 160 + 256;  // 19.2 MB

    int* row_ptr = (int*)d_ws;
    const int rowgroups = (batch + 3) / 4;

    if (ws_size >= need8) {
        unsigned char* wf = (unsigned char*)d_ws + wf_off;
        const int scat_blocks = (nnz + 255) / 256;
        const int rep_blocks  = (in_dim * (OUT_DIM / 2) + 255) / 256;
        setup8_kernel<<<scat_blocks + rep_blocks, 256, 0, stream>>>(
            sp_rows, row_ptr, weights, wf, nnz, batch, in_dim, scat_blocks);
        spmm8w<<<rowgroups * 8, 256, 0, stream>>>(
            row_ptr, sp_cols, sp_vals, wf, bias, out, batch, in_dim);
    } else if (ws_size >= need4) {
        unsigned char* wf = (unsigned char*)d_ws + wf_off;
        row_ptr_scatter<<<(nnz + 255) / 256, 256, 0, stream>>>(
            sp_rows, row_ptr, nnz, batch);
        const int pairs = in_dim * (OUT_DIM / 2);
        repack_f16_sliced<<<(pairs + 255) / 256, 256, 0, stream>>>(
            weights, wf, in_dim);
        spmm_sliced3<<<rowgroups * 4, 256, 0, stream>>>(
            row_ptr, sp_cols, sp_vals, wf, bias, out, batch, in_dim);
    } else {
        row_ptr_scatter<<<(nnz + 255) / 256, 256, 0, stream>>>(
            sp_rows, row_ptr, nnz, batch);
        spmm_wave_f32_kernel<<<(batch + 3) / 4, 256, 0, stream>>>(
            row_ptr, sp_cols, sp_vals, weights, bias, out, batch);
    }
}

// Round 9
// 137.543 us; speedup vs baseline: 1.2202x; 1.1581x over previous
//
#include <hip/hip_runtime.h>

#define OUT_DIM 300

typedef _Float16 half2_t __attribute__((ext_vector_type(2)));
typedef _Float16 half8_t __attribute__((ext_vector_type(8)));

// ---------------------------------------------------------------------------
// Fused setup. Blocks [0, scat_blocks): row_ptr boundary scatter (rows sorted).
// Remainder: repack fp32 weights -> f16, 4 slices {80,80,80,60} cols, stride
// 160 B. half2-chunk k (cols 2k,2k+1) of row r -> slice s=min(k/40,3),
// kc=k-40s, dst=((s*in_dim)+r)*160 + kc*4. Slice-3 rows: bytes 120..159 pad
// (never zeroed; consumed only by unstored lanes/components).
__global__ __launch_bounds__(256) void setup4_kernel(
    const int* __restrict__ rows, int* __restrict__ row_ptr,
    const float* __restrict__ w, unsigned char* __restrict__ wf,
    int nnz, int batch, int in_dim, int scat_blocks)
{
    if ((int)blockIdx.x < scat_blocks) {
        int i = blockIdx.x * 256 + threadIdx.x;
        if (i >= nnz) return;
        int r = rows[i];
        int prev = (i == 0) ? -1 : rows[i - 1];
        for (int q = prev + 1; q <= r; ++q) row_ptr[q] = i;
        if (i == nnz - 1)
            for (int q = r + 1; q <= batch; ++q) row_ptr[q] = nnz;
        return;
    }
    const int UPR = OUT_DIM / 2;          // 150 half2-chunks per weight row
    int j = ((int)blockIdx.x - scat_blocks) * 256 + threadIdx.x;
    if (j >= in_dim * UPR) return;
    int r = j / UPR;
    int k = j - r * UPR;                  // 0..149 -> cols 2k,2k+1
    int s = k / 40; if (s > 3) s = 3;     // 0..2 for k<120, else 3
    int kc = k - 40 * s;                  // 0..39 (s=3: 0..29)
    float2 f = *(const float2*)(w + (size_t)r * OUT_DIM + 2 * k);
    half2_t h;
    h.x = (_Float16)f.x;
    h.y = (_Float16)f.y;
    *(half2_t*)(wf + ((size_t)s * in_dim + r) * 160 + kc * 4) = h;
}

// ---------------------------------------------------------------------------
// 4-slice wide-load SpMM. Block b: rowgroup b>>2 (4 rows, one per wave),
// slice b&3. Per-XCD gather working set 30000*160 = 4.8 MB (~L2, proven R6).
// Wave: 6 groups x 10 lanes (grp=lane/10; lanes 60..63 grp=6 prefetch next
// round's grp-0 lines). Lane owns half8 chunk ch (8 cols): one dwordx4 + 8
// v_fma_mix per 6 nnz per round; float a[8] register accumulator.
__global__ __launch_bounds__(256) void spmm4w(
    const int* __restrict__ row_ptr,
    const int* __restrict__ cols,
    const float* __restrict__ vals,
    const unsigned char* __restrict__ wf,
    const float* __restrict__ bias,
    float* __restrict__ out,
    int batch, int in_dim)
{
    __shared__ uint2 sh[4][76];

    const int slice = blockIdx.x & 3;
    const int wave  = threadIdx.x >> 6;
    const int lane  = threadIdx.x & 63;
    const int row   = (blockIdx.x >> 2) * 4 + wave;
    if (row >= batch) return;

    const int grp = lane / 10;            // 0..6
    const int ch  = lane - grp * 10;      // 0..9
    const int choff = ch * 16;

    const unsigned char* wslice = wf + (size_t)slice * in_dim * 160;
    uint2* shw = sh[wave];                // wave-private: no __syncthreads

    if (lane < 12) shw[64 + lane] = make_uint2(0u, 0u);  // pad slots, once

    const int lo = row_ptr[row];
    const int hi = row_ptr[row + 1];

    float a0 = 0.f, a1 = 0.f, a2 = 0.f, a3 = 0.f;
    float a4 = 0.f, a5 = 0.f, a6 = 0.f, a7 = 0.f;

    for (int base = lo; base < hi; base += 64) {
        const int rem = hi - base;
        const int cnt = rem < 64 ? rem : 64;

        uint2 ov = make_uint2(0u, 0u);
        if (lane < cnt) {
            ov.x = (unsigned)(cols[base + lane] * 160);   // byte offset
            ov.y = __float_as_uint(vals[base + lane]);
        }
        shw[lane] = ov;

        const int rr  = (cnt + 5) / 6;        // rounds of 6 nnz, <= 11
        const int rrp = (rr + 3) & ~3;        // <= 12 -> max slot 6*11+6 = 72
        for (int r0 = 0; r0 < rrp; r0 += 4) {
#pragma unroll
            for (int u = 0; u < 4; ++u) {
                uint2 q = shw[6 * (r0 + u) + grp];   // per-group broadcast
                float v = __uint_as_float(q.y);
                half8_t wv = *(const half8_t*)(wslice + q.x + choff);
                a0 += v * (float)wv[0];              // v_fma_mix_f32
                a1 += v * (float)wv[1];
                a2 += v * (float)wv[2];
                a3 += v * (float)wv[3];
                a4 += v * (float)wv[4];
                a5 += v * (float)wv[5];
                a6 += v * (float)wv[6];
                a7 += v * (float)wv[7];
            }
        }
        // Zero slots: v=0, off=0 -> +0 via hot line. grp6 = prefetch only.
    }

    // Fold 6 groups: +30, then +10 and +20 of the folded value.
    a0 += __shfl_down(a0, 30); a1 += __shfl_down(a1, 30);
    a2 += __shfl_down(a2, 30); a3 += __shfl_down(a3, 30);
    a4 += __shfl_down(a4, 30); a5 += __shfl_down(a5, 30);
    a6 += __shfl_down(a6, 30); a7 += __shfl_down(a7, 30);

    float f0 = a0 + __shfl_down(a0, 10) + __shfl_down(a0, 20);
    float f1 = a1 + __shfl_down(a1, 10) + __shfl_down(a1, 20);
    float f2 = a2 + __shfl_down(a2, 10) + __shfl_down(a2, 20);
    float f3 = a3 + __shfl_down(a3, 10) + __shfl_down(a3, 20);
    float f4 = a4 + __shfl_down(a4, 10) + __shfl_down(a4, 20);
    float f5 = a5 + __shfl_down(a5, 10) + __shfl_down(a5, 20);
    float f6 = a6 + __shfl_down(a6, 10) + __shfl_down(a6, 20);
    float f7 = a7 + __shfl_down(a7, 10) + __shfl_down(a7, 20);

    const int nlan = (slice == 3) ? 8 : 10;      // storing lanes
    if (lane < nlan) {
        const int col = slice * 80 + lane * 8;   // 16B-aligned
        float* orow = out + (size_t)row * OUT_DIM + col;
        const float4 b0 = *(const float4*)(bias + col);
        float4 s0;
        s0.x = fmaxf(f0 + b0.x, 0.f);
        s0.y = fmaxf(f1 + b0.y, 0.f);
        s0.z = fmaxf(f2 + b0.z, 0.f);
        s0.w = fmaxf(f3 + b0.w, 0.f);
        *(float4*)orow = s0;
        if (slice < 3 || lane < 7) {             // lane7@slice3: cols 296..299 only
            const float4 b1 = *(const float4*)(bias + col + 4);
            float4 s1;
            s1.x = fmaxf(f4 + b1.x, 0.f);
            s1.y = fmaxf(f5 + b1.y, 0.f);
            s1.z = fmaxf(f6 + b1.z, 0.f);
            s1.w = fmaxf(f7 + b1.w, 0.f);
            *(float4*)(orow + 4) = s1;
        }
    }
}

// ---------------------------------------------------------------------------
// Last-resort fp32 path (tiny ws).
__global__ __launch_bounds__(256) void row_ptr_scatter(
    const int* __restrict__ rows, int* __restrict__ row_ptr, int nnz, int batch)
{
    int i = blockIdx.x * 256 + threadIdx.x;
    if (i >= nnz) return;
    int r = rows[i];
    int prev = (i == 0) ? -1 : rows[i - 1];
    for (int q = prev + 1; q <= r; ++q) row_ptr[q] = i;
    if (i == nnz - 1)
        for (int q = r + 1; q <= batch; ++q) row_ptr[q] = nnz;
}

__global__ __launch_bounds__(256) void spmm_wave_f32_kernel(
    const int* __restrict__ row_ptr,
    const int* __restrict__ cols,
    const float* __restrict__ vals,
    const float* __restrict__ weights,
    const float* __restrict__ bias,
    float* __restrict__ out,
    int batch)
{
    const int wave = threadIdx.x >> 6;
    const int lane = threadIdx.x & 63;
    const int row  = blockIdx.x * 4 + wave;
    if (row >= batch) return;

    const int lo = row_ptr[row];
    const int hi = row_ptr[row + 1];
    float4 acc0 = make_float4(0.f, 0.f, 0.f, 0.f);
    float4 acc1 = make_float4(0.f, 0.f, 0.f, 0.f);
    const bool tail = (lane < 75 - 64);

    for (int base = lo; base < hi; base += 64) {
        const int rem = hi - base;
        const int cnt = rem < 64 ? rem : 64;
        int   c = 0;
        float v = 0.0f;
        if (lane < cnt) { c = cols[base + lane]; v = vals[base + lane]; }
        const int rounds = (cnt + 7) & ~7;
        for (int k = 0; k < rounds; k += 8) {
#pragma unroll
            for (int u = 0; u < 8; ++u) {
                const int   cc = __shfl(c, k + u);
                const float vv = __shfl(v, k + u);
                const float4* wrow = (const float4*)(weights + (size_t)cc * OUT_DIM);
                float4 w0 = wrow[lane];
                acc0.x += vv * w0.x; acc0.y += vv * w0.y;
                acc0.z += vv * w0.z; acc0.w += vv * w0.w;
                if (tail) {
                    float4 w1 = wrow[64 + lane];
                    acc1.x += vv * w1.x; acc1.y += vv * w1.y;
                    acc1.z += vv * w1.z; acc1.w += vv * w1.w;
                }
            }
        }
    }

    const float4* b4 = (const float4*)bias;
    float4* orow = (float4*)(out + (size_t)row * OUT_DIM);
    float4 b0 = b4[lane];
    float4 r0;
    r0.x = fmaxf(acc0.x + b0.x, 0.f);
    r0.y = fmaxf(acc0.y + b0.y, 0.f);
    r0.z = fmaxf(acc0.z + b0.z, 0.f);
    r0.w = fmaxf(acc0.w + b0.w, 0.f);
    orow[lane] = r0;
    if (tail) {
        float4 b1 = b4[64 + lane];
        float4 r1;
        r1.x = fmaxf(acc1.x + b1.x, 0.f);
        r1.y = fmaxf(acc1.y + b1.y, 0.f);
        r1.z = fmaxf(acc1.z + b1.z, 0.f);
        r1.w = fmaxf(acc1.w + b1.w, 0.f);
        orow[64 + lane] = r1;
    }
}

// ---------------------------------------------------------------------------
extern "C" void kernel_launch(void* const* d_in, const int* in_sizes, int n_in,
                              void* d_out, int out_size, void* d_ws, size_t ws_size,
                              hipStream_t stream) {
    const int*   sp_rows = (const int*)d_in[0];
    const int*   sp_cols = (const int*)d_in[1];
    const float* sp_vals = (const float*)d_in[2];
    const float* weights = (const float*)d_in[3];
    const float* bias    = (const float*)d_in[4];
    float* out = (float*)d_out;

    const int nnz    = in_sizes[0];
    const int w_elts = in_sizes[3];
    const int in_dim = w_elts / OUT_DIM;           // 30000
    const int batch  = out_size / OUT_DIM;         // 16384

    size_t rp_bytes = (size_t)(batch + 1) * sizeof(int);
    size_t wf_off   = (rp_bytes + 255) & ~(size_t)255;
    size_t need4    = wf_off + (size_t)in_dim * 4 * 160 + 256;  // 19.2 MB

    int* row_ptr = (int*)d_ws;
    const int rowgroups = (batch + 3) / 4;

    if (ws_size >= need4) {
        unsigned char* wf = (unsigned char*)d_ws + wf_off;
        const int scat_blocks = (nnz + 255) / 256;
        const int rep_blocks  = (in_dim * (OUT_DIM / 2) + 255) / 256;
        setup4_kernel<<<scat_blocks + rep_blocks, 256, 0, stream>>>(
            sp_rows, row_ptr, weights, wf, nnz, batch, in_dim, scat_blocks);
        spmm4w<<<rowgroups * 4, 256, 0, stream>>>(
            row_ptr, sp_cols, sp_vals, wf, bias, out, batch, in_dim);
    } else {
        row_ptr_scatter<<<(nnz + 255) / 256, 256, 0, stream>>>(
            sp_rows, row_ptr, nnz, batch);
        spmm_wave_f32_kernel<<<(batch + 3) / 4, 256, 0, stream>>>(
            row_ptr, sp_cols, sp_vals, weights, bias, out, batch);
    }
}

// Round 11
// 135.458 us; speedup vs baseline: 1.2390x; 1.0154x over previous
//
#include <hip/hip_runtime.h>

#define OUT_DIM 300

typedef _Float16 half2_t __attribute__((ext_vector_type(2)));
typedef _Float16 half8_t __attribute__((ext_vector_type(8)));
typedef unsigned int uint32x4_t __attribute__((ext_vector_type(4)));

// ---------------------------------------------------------------------------
// Fused setup. Blocks [0, scat_blocks): row_ptr boundary scatter (rows sorted).
// Remainder: repack fp32 weights -> f16, 4 slices {80,80,80,60} cols, stride
// 160 B. half2-chunk k (cols 2k,2k+1) of row r -> slice s=min(k/40,3),
// kc=k-40s, dst=((s*in_dim)+r)*160 + kc*4.
__global__ __launch_bounds__(256) void setup4_kernel(
    const int* __restrict__ rows, int* __restrict__ row_ptr,
    const float* __restrict__ w, unsigned char* __restrict__ wf,
    int nnz, int batch, int in_dim, int scat_blocks)
{
    if ((int)blockIdx.x < scat_blocks) {
        int i = blockIdx.x * 256 + threadIdx.x;
        if (i >= nnz) return;
        int r = rows[i];
        int prev = (i == 0) ? -1 : rows[i - 1];
        for (int q = prev + 1; q <= r; ++q) row_ptr[q] = i;
        if (i == nnz - 1)
            for (int q = r + 1; q <= batch; ++q) row_ptr[q] = nnz;
        return;
    }
    const int UPR = OUT_DIM / 2;          // 150 half2-chunks per weight row
    int j = ((int)blockIdx.x - scat_blocks) * 256 + threadIdx.x;
    if (j >= in_dim * UPR) return;
    int r = j / UPR;
    int k = j - r * UPR;                  // 0..149 -> cols 2k,2k+1
    int s = k / 40; if (s > 3) s = 3;     // 0..2 for k<120, else 3
    int kc = k - 40 * s;                  // 0..39 (s=3: 0..29)
    float2 f = *(const float2*)(w + (size_t)r * OUT_DIM + 2 * k);
    half2_t h;
    h.x = (_Float16)f.x;
    h.y = (_Float16)f.y;
    *(half2_t*)(wf + ((size_t)s * in_dim + r) * 160 + kc * 4) = h;
}

// ---------------------------------------------------------------------------
// 4-slice wide-load SpMM, R9 structure, ONE change: the weight gather is a
// buffer load with aux=1 (sc0 -> L1-bypass, served from L2). Theory: the
// ~7.5 TB/s demand plateau across R6/R8/R9 is a per-CU L1 fill-queue limit
// (~42 outstanding lines); sc0 tracks fills in the wave vmcnt queue instead.
__global__ __launch_bounds__(256) void spmm4w(
    const int* __restrict__ row_ptr,
    const int* __restrict__ cols,
    const float* __restrict__ vals,
    const unsigned char* __restrict__ wf,
    const float* __restrict__ bias,
    float* __restrict__ out,
    int batch, int in_dim)
{
    __shared__ uint2 sh[4][76];

    const int slice = blockIdx.x & 3;
    const int wave  = threadIdx.x >> 6;
    const int lane  = threadIdx.x & 63;
    const int row   = (blockIdx.x >> 2) * 4 + wave;
    if (row >= batch) return;

    const int grp = lane / 10;            // 0..6 (6 = prefetch lanes 60..63)
    const int ch  = lane - grp * 10;      // 0..9
    const int choff = ch * 16;

    const unsigned char* wslice = wf + (size_t)slice * in_dim * 160;

    // Buffer SRD over this slice: stride=0 (raw), num_records = byte size,
    // word3 = 0x00020000 (raw untyped dword access).
    __amdgpu_buffer_rsrc_t rsrc = __builtin_amdgcn_make_buffer_rsrc(
        (void*)wslice, (short)0, in_dim * 160, 0x00020000);

    uint2* shw = sh[wave];                // wave-private: no __syncthreads
    if (lane < 12) shw[64 + lane] = make_uint2(0u, 0u);  // pad slots, once

    const int lo = row_ptr[row];
    const int hi = row_ptr[row + 1];

    float a0 = 0.f, a1 = 0.f, a2 = 0.f, a3 = 0.f;
    float a4 = 0.f, a5 = 0.f, a6 = 0.f, a7 = 0.f;

    for (int base = lo; base < hi; base += 64) {
        const int rem = hi - base;
        const int cnt = rem < 64 ? rem : 64;

        uint2 ov = make_uint2(0u, 0u);
        if (lane < cnt) {
            ov.x = (unsigned)(cols[base + lane] * 160);   // byte offset
            ov.y = __float_as_uint(vals[base + lane]);
        }
        shw[lane] = ov;

        const int rr  = (cnt + 5) / 6;        // rounds of 6 nnz, <= 11
        const int rrp = (rr + 3) & ~3;        // <= 12 -> max slot 6*11+6 = 72
        for (int r0 = 0; r0 < rrp; r0 += 4) {
#pragma unroll
            for (int u = 0; u < 4; ++u) {
                uint2 q = shw[6 * (r0 + u) + grp];   // per-group broadcast
                float v = __uint_as_float(q.y);
                uint32x4_t raw = __builtin_amdgcn_raw_buffer_load_b128(
                    rsrc, (int)(q.x + choff), 0, /*aux: sc0*/ 1);
                half8_t wv = __builtin_bit_cast(half8_t, raw);
                a0 += v * (float)wv[0];              // v_fma_mix_f32
                a1 += v * (float)wv[1];
                a2 += v * (float)wv[2];
                a3 += v * (float)wv[3];
                a4 += v * (float)wv[4];
                a5 += v * (float)wv[5];
                a6 += v * (float)wv[6];
                a7 += v * (float)wv[7];
            }
        }
        // Zero slots: v=0, off=0 -> +0 via hot line. grp6 = prefetch only.
    }

    // Fold 6 groups: +30, then +10 and +20 of the folded value.
    a0 += __shfl_down(a0, 30); a1 += __shfl_down(a1, 30);
    a2 += __shfl_down(a2, 30); a3 += __shfl_down(a3, 30);
    a4 += __shfl_down(a4, 30); a5 += __shfl_down(a5, 30);
    a6 += __shfl_down(a6, 30); a7 += __shfl_down(a7, 30);

    float f0 = a0 + __shfl_down(a0, 10) + __shfl_down(a0, 20);
    float f1 = a1 + __shfl_down(a1, 10) + __shfl_down(a1, 20);
    float f2 = a2 + __shfl_down(a2, 10) + __shfl_down(a2, 20);
    float f3 = a3 + __shfl_down(a3, 10) + __shfl_down(a3, 20);
    float f4 = a4 + __shfl_down(a4, 10) + __shfl_down(a4, 20);
    float f5 = a5 + __shfl_down(a5, 10) + __shfl_down(a5, 20);
    float f6 = a6 + __shfl_down(a6, 10) + __shfl_down(a6, 20);
    float f7 = a7 + __shfl_down(a7, 10) + __shfl_down(a7, 20);

    const int nlan = (slice == 3) ? 8 : 10;      // storing lanes
    if (lane < nlan) {
        const int col = slice * 80 + lane * 8;   // 16B-aligned
        float* orow = out + (size_t)row * OUT_DIM + col;
        const float4 b0 = *(const float4*)(bias + col);
        float4 s0;
        s0.x = fmaxf(f0 + b0.x, 0.f);
        s0.y = fmaxf(f1 + b0.y, 0.f);
        s0.z = fmaxf(f2 + b0.z, 0.f);
        s0.w = fmaxf(f3 + b0.w, 0.f);
        *(float4*)orow = s0;
        if (slice < 3 || lane < 7) {             // lane7@slice3: cols 296..299 only
            const float4 b1 = *(const float4*)(bias + col + 4);
            float4 s1;
            s1.x = fmaxf(f4 + b1.x, 0.f);
            s1.y = fmaxf(f5 + b1.y, 0.f);
            s1.z = fmaxf(f6 + b1.z, 0.f);
            s1.w = fmaxf(f7 + b1.w, 0.f);
            *(float4*)(orow + 4) = s1;
        }
    }
}

// ---------------------------------------------------------------------------
// Last-resort fp32 path (tiny ws).
__global__ __launch_bounds__(256) void row_ptr_scatter(
    const int* __restrict__ rows, int* __restrict__ row_ptr, int nnz, int batch)
{
    int i = blockIdx.x * 256 + threadIdx.x;
    if (i >= nnz) return;
    int r = rows[i];
    int prev = (i == 0) ? -1 : rows[i - 1];
    for (int q = prev + 1; q <= r; ++q) row_ptr[q] = i;
    if (i == nnz - 1)
        for (int q = r + 1; q <= batch; ++q) row_ptr[q] = nnz;
}

__global__ __launch_bounds__(256) void spmm_wave_f32_kernel(
    const int* __restrict__ row_ptr,
    const int* __restrict__ cols,
    const float* __restrict__ vals,
    const float* __restrict__ weights,
    const float* __restrict__ bias,
    float* __restrict__ out,
    int batch)
{
    const int wave = threadIdx.x >> 6;
    const int lane = threadIdx.x & 63;
    const int row  = blockIdx.x * 4 + wave;
    if (row >= batch) return;

    const int lo = row_ptr[row];
    const int hi = row_ptr[row + 1];
    float4 acc0 = make_float4(0.f, 0.f, 0.f, 0.f);
    float4 acc1 = make_float4(0.f, 0.f, 0.f, 0.f);
    const bool tail = (lane < 75 - 64);

    for (int base = lo; base < hi; base += 64) {
        const int rem = hi - base;
        const int cnt = rem < 64 ? rem : 64;
        int   c = 0;
        float v = 0.0f;
        if (lane < cnt) { c = cols[base + lane]; v = vals[base + lane]; }
        const int rounds = (cnt + 7) & ~7;
        for (int k = 0; k < rounds; k += 8) {
#pragma unroll
            for (int u = 0; u < 8; ++u) {
                const int   cc = __shfl(c, k + u);
                const float vv = __shfl(v, k + u);
                const float4* wrow = (const float4*)(weights + (size_t)cc * OUT_DIM);
                float4 w0 = wrow[lane];
                acc0.x += vv * w0.x; acc0.y += vv * w0.y;
                acc0.z += vv * w0.z; acc0.w += vv * w0.w;
                if (tail) {
                    float4 w1 = wrow[64 + lane];
                    acc1.x += vv * w1.x; acc1.y += vv * w1.y;
                    acc1.z += vv * w1.z; acc1.w += vv * w1.w;
                }
            }
        }
    }

    const float4* b4 = (const float4*)bias;
    float4* orow = (float4*)(out + (size_t)row * OUT_DIM);
    float4 b0 = b4[lane];
    float4 r0;
    r0.x = fmaxf(acc0.x + b0.x, 0.f);
    r0.y = fmaxf(acc0.y + b0.y, 0.f);
    r0.z = fmaxf(acc0.z + b0.z, 0.f);
    r0.w = fmaxf(acc0.w + b0.w, 0.f);
    orow[lane] = r0;
    if (tail) {
        float4 b1 = b4[64 + lane];
        float4 r1;
        r1.x = fmaxf(acc1.x + b1.x, 0.f);
        r1.y = fmaxf(acc1.y + b1.y, 0.f);
        r1.z = fmaxf(acc1.z + b1.z, 0.f);
        r1.w = fmaxf(acc1.w + b1.w, 0.f);
        orow[64 + lane] = r1;
    }
}

// ---------------------------------------------------------------------------
extern "C" void kernel_launch(void* const* d_in, const int* in_sizes, int n_in,
                              void* d_out, int out_size, void* d_ws, size_t ws_size,
                              hipStream_t stream) {
    const int*   sp_rows = (const int*)d_in[0];
    const int*   sp_cols = (const int*)d_in[1];
    const float* sp_vals = (const float*)d_in[2];
    const float* weights = (const float*)d_in[3];
    const float* bias    = (const float*)d_in[4];
    float* out = (float*)d_out;

    const int nnz    = in_sizes[0];
    const int w_elts = in_sizes[3];
    const int in_dim = w_elts / OUT_DIM;           // 30000
    const int batch  = out_size / OUT_DIM;         // 16384

    size_t rp_bytes = (size_t)(batch + 1) * sizeof(int);
    size_t wf_off   = (rp_bytes + 255) & ~(size_t)255;
    size_t need4    = wf_off + (size_t)in_dim * 4 * 160 + 256;  // 19.2 MB

    int* row_ptr = (int*)d_ws;
    const int rowgroups = (batch + 3) / 4;

    if (ws_size >= need4) {
        unsigned char* wf = (unsigned char*)d_ws + wf_off;
        const int scat_blocks = (nnz + 255) / 256;
        const int rep_blocks  = (in_dim * (OUT_DIM / 2) + 255) / 256;
        setup4_kernel<<<scat_blocks + rep_blocks, 256, 0, stream>>>(
            sp_rows, row_ptr, weights, wf, nnz, batch, in_dim, scat_blocks);
        spmm4w<<<rowgroups * 4, 256, 0, stream>>>(
            row_ptr, sp_cols, sp_vals, wf, bias, out, batch, in_dim);
    } else {
        row_ptr_scatter<<<(nnz + 255) / 256, 256, 0, stream>>>(
            sp_rows, row_ptr, nnz, batch);
        spmm_wave_f32_kernel<<<(batch + 3) / 4, 256, 0, stream>>>(
            row_ptr, sp_cols, sp_vals, weights, bias, out, batch);
    }
}